// Round 4
// baseline (554.372 us; speedup 1.0000x reference)
//
#include <hip/hip_runtime.h>

#define N_NODES 100000
#define N_EDGES 1600000
#define NB_SCAN 49  // ceil(100000/2048)

// ---------------- CSR build ----------------

__global__ void k_zero(int* __restrict__ p, int n) {
    int i = blockIdx.x * blockDim.x + threadIdx.x;
    if (i < n) p[i] = 0;
}

__global__ void k_count(const int* __restrict__ dst, int* __restrict__ cnt) {
    int e = blockIdx.x * blockDim.x + threadIdx.x;
    if (e < N_EDGES) atomicAdd(&cnt[dst[e]], 1);
}

__global__ void k_partial(const int* __restrict__ cnt, int* __restrict__ part) {
    __shared__ int red[256];
    int t = threadIdx.x;
    int base = blockIdx.x * 2048 + t * 8;
    int s = 0;
    if (base < N_NODES) {  // N_NODES % 8 == 0
        const int4* p = (const int4*)(cnt + base);
        int4 a = p[0], b = p[1];
        s = a.x + a.y + a.z + a.w + b.x + b.y + b.z + b.w;
    }
    red[t] = s;
    __syncthreads();
    for (int d = 128; d > 0; d >>= 1) {
        if (t < d) red[t] += red[t + d];
        __syncthreads();
    }
    if (t == 0) part[blockIdx.x] = red[0];
}

__global__ void k_scan_part(int* __restrict__ part, int nb) {
    int lane = threadIdx.x;
    int v = (lane < nb) ? part[lane] : 0;
    int incl = v;
    #pragma unroll
    for (int d = 1; d < 64; d <<= 1) {
        int u = __shfl_up(incl, d, 64);
        if (lane >= d) incl += u;
    }
    if (lane < nb) part[lane] = incl - v;
}

__global__ void k_scan_chunks(const int* __restrict__ cnt, const int* __restrict__ part,
                              int* __restrict__ off) {
    __shared__ int wtot[4];
    __shared__ int wexc[4];
    int t = threadIdx.x, b = blockIdx.x;
    int base = b * 2048 + t * 8;
    int4 a = {0, 0, 0, 0}, c = {0, 0, 0, 0};
    if (base < N_NODES) {
        const int4* p = (const int4*)(cnt + base);
        a = p[0];
        c = p[1];
    }
    int s0 = a.x, s1 = s0 + a.y, s2 = s1 + a.z, s3 = s2 + a.w;
    int s4 = s3 + c.x, s5 = s4 + c.y, s6 = s5 + c.z, s7 = s6 + c.w;
    int tot = s7;
    int lane = t & 63, wid = t >> 6;
    int incl = tot;
    #pragma unroll
    for (int d = 1; d < 64; d <<= 1) {
        int u = __shfl_up(incl, d, 64);
        if (lane >= d) incl += u;
    }
    if (lane == 63) wtot[wid] = incl;
    __syncthreads();
    if (t == 0) {
        int r = 0;
        for (int i = 0; i < 4; i++) { int v = wtot[i]; wexc[i] = r; r += v; }
    }
    __syncthreads();
    int texc = incl - tot + wexc[wid] + part[b];
    if (base < N_NODES) {
        int4 o0 = {texc, texc + s0, texc + s1, texc + s2};
        int4 o1 = {texc + s3, texc + s4, texc + s5, texc + s6};
        ((int4*)(off + base))[0] = o0;
        ((int4*)(off + base))[1] = o1;
    }
}

__global__ void k_scatter64(const int* __restrict__ dst, const int* __restrict__ src,
                            const int* __restrict__ off, int* __restrict__ cur,
                            unsigned long long* __restrict__ code64) {
    int e = blockIdx.x * blockDim.x + threadIdx.x;
    if (e < N_EDGES) {
        int d = dst[e];
        int p = off[d] + atomicAdd(&cur[d], 1);
        code64[p] = ((unsigned long long)(unsigned)src[e] << 32) | (unsigned)e;
    }
}

__global__ void k_scatter32(const int* __restrict__ dst, const int* __restrict__ off,
                            int* __restrict__ cur, int* __restrict__ eid) {
    int e = blockIdx.x * blockDim.x + threadIdx.x;
    if (e < N_EDGES) {
        int d = dst[e];
        int p = off[d] + atomicAdd(&cur[d], 1);
        eid[p] = e;
    }
}

// ---------------- weight fold: Wc = Wa_N @ Wm, bc = Wa_N @ bm + ba ----------------
__global__ void k_prec(const float* __restrict__ Wm, const float* __restrict__ bm,
                       const float* __restrict__ Wa, const float* __restrict__ ba,
                       float* __restrict__ Wc, float* __restrict__ bc) {
    int o = blockIdx.x;       // 64
    int k = threadIdx.x;      // 128
    const float* war = Wa + o * 128 + 64;
    float s = 0.f;
    #pragma unroll 8
    for (int j = 0; j < 64; j++) s += war[j] * Wm[j * 128 + k];
    Wc[o * 128 + k] = s;
    if (k == 0) {
        float t = ba[o];
        for (int j = 0; j < 64; j++) t += war[j] * bm[j];
        bc[o] = t;
    }
}

// ---------------- wave-per-node aggregation (writes MEAN) ----------------
__device__ __forceinline__ float4 ld_feat(const float* __restrict__ nf,
                                          const float* __restrict__ ef,
                                          unsigned long long c, int slot) {
    unsigned e = (unsigned)c;
    unsigned sv = (unsigned)(c >> 32);
    const float* p = (slot < 16) ? (nf + (size_t)sv * 64 + slot * 4)
                                 : (ef + (size_t)e * 64 + (slot - 16) * 4);
    return *(const float4*)p;
}

__global__ __launch_bounds__(256) void k_agg(
    const float* __restrict__ nf, const float* __restrict__ ef,
    const int* __restrict__ cnt, const int* __restrict__ off,
    const unsigned long long* __restrict__ code64, float* __restrict__ aggG) {
    int tid = threadIdx.x, lane = tid & 63, wid = tid >> 6;
    int n = blockIdx.x * 4 + wid;
    if (n >= N_NODES) return;
    int slot = lane & 31, half = lane >> 5;
    int st = off[n], deg = cnt[n];
    int pend = st + deg;
    float4 acc = make_float4(0.f, 0.f, 0.f, 0.f);
    int p = st + half;
    for (; p + 6 < pend; p += 8) {
        unsigned long long c0 = code64[p];
        unsigned long long c1 = code64[p + 2];
        unsigned long long c2 = code64[p + 4];
        unsigned long long c3 = code64[p + 6];
        float4 a0 = ld_feat(nf, ef, c0, slot);
        float4 a1 = ld_feat(nf, ef, c1, slot);
        float4 a2 = ld_feat(nf, ef, c2, slot);
        float4 a3 = ld_feat(nf, ef, c3, slot);
        acc.x += a0.x + a1.x + a2.x + a3.x;
        acc.y += a0.y + a1.y + a2.y + a3.y;
        acc.z += a0.z + a1.z + a2.z + a3.z;
        acc.w += a0.w + a1.w + a2.w + a3.w;
    }
    for (; p < pend; p += 2) {
        unsigned long long c = code64[p];
        float4 a = ld_feat(nf, ef, c, slot);
        acc.x += a.x; acc.y += a.y; acc.z += a.z; acc.w += a.w;
    }
    acc.x += __shfl_xor(acc.x, 32, 64);
    acc.y += __shfl_xor(acc.y, 32, 64);
    acc.z += __shfl_xor(acc.z, 32, 64);
    acc.w += __shfl_xor(acc.w, 32, 64);
    if (half == 0) {
        float inv = (deg > 0) ? 1.f / (float)deg : 0.f;
        acc.x *= inv; acc.y *= inv; acc.z *= inv; acc.w *= inv;
        *(float4*)(aggG + (size_t)n * 128 + slot * 4) = acc;
    }
}

// ---------------- apply: out = relu(WaH @ h + Wc @ mean + bias) ----------------
// 256 threads, 64 nodes/block. LDS = mean tile only (33.8 KB -> 4 blocks/CU).
__global__ __launch_bounds__(256, 4) void k_apply(
    const float* __restrict__ nf, const float* __restrict__ aggG,
    const int* __restrict__ cnt,
    const float* __restrict__ Wa, const float* __restrict__ Wc,
    const float* __restrict__ ba, const float* __restrict__ bc,
    float* __restrict__ out) {
    __shared__ __align__(16) float am[64][132];
    __shared__ float degl[64];

    int tid = threadIdx.x;
    int base = blockIdx.x * 64;

    // stage mean tile coalesced
    {
        const float4* g4 = (const float4*)aggG;
        #pragma unroll
        for (int r = 0; r < 8; r++) {
            int f = r * 256 + tid;   // 0..2047
            int row = f >> 5, c4 = f & 31;
            float4 v = make_float4(0.f, 0.f, 0.f, 0.f);
            if (base + row < N_NODES) v = g4[(size_t)(base + row) * 32 + c4];
            *(float4*)&am[row][c4 * 4] = v;
        }
        if (tid < 64) degl[tid] = (base + tid < N_NODES) ? (float)cnt[base + tid] : 0.f;
    }
    __syncthreads();

    int og = (tid & 15) * 4;
    int ng = (tid >> 4) * 4;
    float acc[4][4] = {};
    const float4* Wa4 = (const float4*)Wa;  // row o = 32 float4, first 16 = h-part
    const float4* Wc4 = (const float4*)Wc;  // row o = 32 float4

    // part 1: h from global (16-lane groups share addresses -> L1 broadcast)
    #pragma unroll 4
    for (int k4 = 0; k4 < 16; k4++) {
        float4 hv[4], wv[4];
        #pragma unroll
        for (int i = 0; i < 4; i++) {
            int n = base + ng + i;
            hv[i] = (n < N_NODES) ? ((const float4*)(nf + (size_t)n * 64))[k4]
                                  : make_float4(0.f, 0.f, 0.f, 0.f);
        }
        #pragma unroll
        for (int j = 0; j < 4; j++) wv[j] = Wa4[(og + j) * 32 + k4];
        #pragma unroll
        for (int i = 0; i < 4; i++)
            #pragma unroll
            for (int j = 0; j < 4; j++)
                acc[i][j] += hv[i].x * wv[j].x + hv[i].y * wv[j].y +
                             hv[i].z * wv[j].z + hv[i].w * wv[j].w;
    }
    // part 2: mean from LDS
    #pragma unroll 4
    for (int k4 = 0; k4 < 32; k4++) {
        float4 av[4], wv[4];
        #pragma unroll
        for (int i = 0; i < 4; i++) av[i] = *(const float4*)&am[ng + i][k4 * 4];
        #pragma unroll
        for (int j = 0; j < 4; j++) wv[j] = Wc4[(og + j) * 32 + k4];
        #pragma unroll
        for (int i = 0; i < 4; i++)
            #pragma unroll
            for (int j = 0; j < 4; j++)
                acc[i][j] += av[i].x * wv[j].x + av[i].y * wv[j].y +
                             av[i].z * wv[j].z + av[i].w * wv[j].w;
    }
    // epilogue: bias select + relu
    #pragma unroll
    for (int i = 0; i < 4; i++) {
        int n = base + ng + i;
        if (n < N_NODES) {
            float d = degl[ng + i];
            float4 o;
            o.x = fmaxf(acc[i][0] + ((d > 0.f) ? bc[og + 0] : ba[og + 0]), 0.f);
            o.y = fmaxf(acc[i][1] + ((d > 0.f) ? bc[og + 1] : ba[og + 1]), 0.f);
            o.z = fmaxf(acc[i][2] + ((d > 0.f) ? bc[og + 2] : ba[og + 2]), 0.f);
            o.w = fmaxf(acc[i][3] + ((d > 0.f) ? bc[og + 3] : ba[og + 3]), 0.f);
            *(float4*)&out[(size_t)n * 64 + og] = o;
        }
    }
}

// ---------------- fallback (round-1 kernel, known good) ----------------
__global__ __launch_bounds__(256) void k_node_fb(
    const float* __restrict__ nf, const float* __restrict__ ef,
    const int* __restrict__ src, const int* __restrict__ cnt,
    const int* __restrict__ off, const int* __restrict__ eid,
    const float* __restrict__ Wm, const float* __restrict__ bm,
    const float* __restrict__ Wa, const float* __restrict__ ba,
    float* __restrict__ out) {
    __shared__ __align__(16) float agg[64][132];
    __shared__ __align__(16) float hn[64][68];
    __shared__ float degl[64];

    int tid = threadIdx.x, lane = tid & 63, wid = tid >> 6;
    int base = blockIdx.x * 64;

    for (int q = 0; q < 16; q++) {
        int nl = wid * 16 + q;
        int n = base + nl;
        float sh = 0.f, se = 0.f;
        int dg = 0;
        if (n < N_NODES) {
            dg = cnt[n];
            int st = off[n];
            for (int c0 = 0; c0 < dg; c0 += 64) {
                int m = dg - c0;
                if (m > 64) m = 64;
                int e_l = 0, s_l = 0;
                if (lane < m) {
                    e_l = eid[st + c0 + lane];
                    s_l = src[e_l];
                }
                for (int j = 0; j < m; j++) {
                    int e = __shfl(e_l, j, 64);
                    int s = __shfl(s_l, j, 64);
                    sh += nf[(size_t)s * 64 + lane];
                    se += ef[(size_t)e * 64 + lane];
                }
            }
        }
        agg[nl][lane] = sh;
        agg[nl][64 + lane] = se;
        if (lane == 0) degl[nl] = (float)dg;
    }
    __syncthreads();

    int og = (tid & 15) * 4;
    int ng = (tid >> 4) * 4;
    float acc[4][4] = {};
    const float4* Wm4 = (const float4*)Wm;
    #pragma unroll 4
    for (int k4 = 0; k4 < 32; k4++) {
        float4 av[4], wv[4];
        #pragma unroll
        for (int i = 0; i < 4; i++) av[i] = *(const float4*)&agg[ng + i][k4 * 4];
        #pragma unroll
        for (int j = 0; j < 4; j++) wv[j] = Wm4[(og + j) * 32 + k4];
        #pragma unroll
        for (int i = 0; i < 4; i++)
            #pragma unroll
            for (int j = 0; j < 4; j++)
                acc[i][j] += av[i].x * wv[j].x + av[i].y * wv[j].y +
                             av[i].z * wv[j].z + av[i].w * wv[j].w;
    }
    #pragma unroll
    for (int i = 0; i < 4; i++) {
        float d = degl[ng + i];
        float inv = (d > 0.f) ? 1.f / d : 0.f;
        #pragma unroll
        for (int j = 0; j < 4; j++) {
            float v = (d > 0.f) ? acc[i][j] * inv + bm[og + j] : 0.f;
            hn[ng + i][og + j] = v;
        }
    }
    __syncthreads();

    float acc2[4][4] = {};
    const float4* Wa4 = (const float4*)Wa;
    #pragma unroll 4
    for (int k4 = 0; k4 < 16; k4++) {
        float4 hv[4], wv[4];
        #pragma unroll
        for (int i = 0; i < 4; i++) {
            int n = base + ng + i;
            if (n < N_NODES)
                hv[i] = ((const float4*)(nf + (size_t)n * 64))[k4];
            else
                hv[i] = make_float4(0.f, 0.f, 0.f, 0.f);
        }
        #pragma unroll
        for (int j = 0; j < 4; j++) wv[j] = Wa4[(og + j) * 32 + k4];
        #pragma unroll
        for (int i = 0; i < 4; i++)
            #pragma unroll
            for (int j = 0; j < 4; j++)
                acc2[i][j] += hv[i].x * wv[j].x + hv[i].y * wv[j].y +
                              hv[i].z * wv[j].z + hv[i].w * wv[j].w;
    }
    #pragma unroll 4
    for (int k4 = 0; k4 < 16; k4++) {
        float4 hv[4], wv[4];
        #pragma unroll
        for (int i = 0; i < 4; i++) hv[i] = *(const float4*)&hn[ng + i][k4 * 4];
        #pragma unroll
        for (int j = 0; j < 4; j++) wv[j] = Wa4[(og + j) * 32 + 16 + k4];
        #pragma unroll
        for (int i = 0; i < 4; i++)
            #pragma unroll
            for (int j = 0; j < 4; j++)
                acc2[i][j] += hv[i].x * wv[j].x + hv[i].y * wv[j].y +
                              hv[i].z * wv[j].z + hv[i].w * wv[j].w;
    }
    #pragma unroll
    for (int i = 0; i < 4; i++) {
        int n = base + ng + i;
        if (n < N_NODES) {
            float4 o;
            o.x = fmaxf(acc2[i][0] + ba[og + 0], 0.f);
            o.y = fmaxf(acc2[i][1] + ba[og + 1], 0.f);
            o.z = fmaxf(acc2[i][2] + ba[og + 2], 0.f);
            o.w = fmaxf(acc2[i][3] + ba[og + 3], 0.f);
            *(float4*)&out[(size_t)n * 64 + og] = o;
        }
    }
}

extern "C" void kernel_launch(void* const* d_in, const int* in_sizes, int n_in,
                              void* d_out, int out_size, void* d_ws, size_t ws_size,
                              hipStream_t stream) {
    const float* nf = (const float*)d_in[0];
    const float* ef = (const float*)d_in[1];
    const int* src = (const int*)d_in[2];
    const int* dst = (const int*)d_in[3];
    const float* Wm = (const float*)d_in[4];
    const float* bm = (const float*)d_in[5];
    const float* Wa = (const float*)d_in[6];
    const float* ba = (const float*)d_in[7];
    float* out = (float*)d_out;

    // ws layout: cnt[N], cur[N], part[64] (zeroed), off[N], code64[E], aggG[N*128], Wc[64*128], bc[64]
    int* cnt = (int*)d_ws;
    int* cur = cnt + N_NODES;
    int* part = cur + N_NODES;
    int* off = part + 64;
    size_t csr_bytes = (size_t)(3 * N_NODES + 64) * 4;  // 1,200,256 B (8B-aligned)

    int nz = 2 * N_NODES + 64;  // cnt, cur, part
    k_zero<<<(nz + 255) / 256, 256, 0, stream>>>(cnt, nz);
    k_count<<<(N_EDGES + 255) / 256, 256, 0, stream>>>(dst, cnt);
    k_partial<<<NB_SCAN, 256, 0, stream>>>(cnt, part);
    k_scan_part<<<1, 64, 0, stream>>>(part, NB_SCAN);
    k_scan_chunks<<<NB_SCAN, 256, 0, stream>>>(cnt, part, off);

    size_t need = csr_bytes + (size_t)N_EDGES * 8 + (size_t)N_NODES * 128 * 4 +
                  (size_t)64 * 128 * 4 + 256;
    if (ws_size >= need) {
        unsigned long long* code64 = (unsigned long long*)((char*)d_ws + csr_bytes);
        float* aggG = (float*)((char*)code64 + (size_t)N_EDGES * 8);
        float* Wc = aggG + (size_t)N_NODES * 128;
        float* bc = Wc + 64 * 128;
        k_prec<<<64, 128, 0, stream>>>(Wm, bm, Wa, ba, Wc, bc);
        k_scatter64<<<(N_EDGES + 255) / 256, 256, 0, stream>>>(dst, src, off, cur, code64);
        k_agg<<<N_NODES / 4, 256, 0, stream>>>(nf, ef, cnt, off, code64, aggG);
        k_apply<<<(N_NODES + 63) / 64, 256, 0, stream>>>(nf, aggG, cnt, Wa, Wc, ba, bc, out);
    } else {
        int* eid = (int*)((char*)d_ws + csr_bytes);
        k_scatter32<<<(N_EDGES + 255) / 256, 256, 0, stream>>>(dst, off, cur, eid);
        k_node_fb<<<(N_NODES + 63) / 64, 256, 0, stream>>>(nf, ef, src, cnt, off, eid,
                                                           Wm, bm, Wa, ba, out);
    }
}

// Round 5
// 455.535 us; speedup vs baseline: 1.2170x; 1.2170x over previous
//
#include <hip/hip_runtime.h>

#define N_NODES 100000
#define N_EDGES 1600000
#define NB_SCAN 49  // ceil(100000/2048)

// ---------------- CSR build ----------------

__global__ void k_zero(int* __restrict__ p, int n) {
    int i = blockIdx.x * blockDim.x + threadIdx.x;
    if (i < n) p[i] = 0;
}

__global__ void k_count(const int* __restrict__ dst, int* __restrict__ cnt) {
    int e = blockIdx.x * blockDim.x + threadIdx.x;
    if (e < N_EDGES) atomicAdd(&cnt[dst[e]], 1);
}

__global__ void k_partial(const int* __restrict__ cnt, int* __restrict__ part) {
    __shared__ int red[256];
    int t = threadIdx.x;
    int base = blockIdx.x * 2048 + t * 8;
    int s = 0;
    if (base < N_NODES) {  // N_NODES % 8 == 0
        const int4* p = (const int4*)(cnt + base);
        int4 a = p[0], b = p[1];
        s = a.x + a.y + a.z + a.w + b.x + b.y + b.z + b.w;
    }
    red[t] = s;
    __syncthreads();
    for (int d = 128; d > 0; d >>= 1) {
        if (t < d) red[t] += red[t + d];
        __syncthreads();
    }
    if (t == 0) part[blockIdx.x] = red[0];
}

__global__ void k_scan_part(int* __restrict__ part, int nb) {
    int lane = threadIdx.x;
    int v = (lane < nb) ? part[lane] : 0;
    int incl = v;
    #pragma unroll
    for (int d = 1; d < 64; d <<= 1) {
        int u = __shfl_up(incl, d, 64);
        if (lane >= d) incl += u;
    }
    if (lane < nb) part[lane] = incl - v;
}

__global__ void k_scan_chunks(const int* __restrict__ cnt, const int* __restrict__ part,
                              int* __restrict__ off) {
    __shared__ int wtot[4];
    __shared__ int wexc[4];
    int t = threadIdx.x, b = blockIdx.x;
    int base = b * 2048 + t * 8;
    int4 a = {0, 0, 0, 0}, c = {0, 0, 0, 0};
    if (base < N_NODES) {
        const int4* p = (const int4*)(cnt + base);
        a = p[0];
        c = p[1];
    }
    int s0 = a.x, s1 = s0 + a.y, s2 = s1 + a.z, s3 = s2 + a.w;
    int s4 = s3 + c.x, s5 = s4 + c.y, s6 = s5 + c.z, s7 = s6 + c.w;
    int tot = s7;
    int lane = t & 63, wid = t >> 6;
    int incl = tot;
    #pragma unroll
    for (int d = 1; d < 64; d <<= 1) {
        int u = __shfl_up(incl, d, 64);
        if (lane >= d) incl += u;
    }
    if (lane == 63) wtot[wid] = incl;
    __syncthreads();
    if (t == 0) {
        int r = 0;
        for (int i = 0; i < 4; i++) { int v = wtot[i]; wexc[i] = r; r += v; }
    }
    __syncthreads();
    int texc = incl - tot + wexc[wid] + part[b];
    if (base < N_NODES) {
        int4 o0 = {texc, texc + s0, texc + s1, texc + s2};
        int4 o1 = {texc + s3, texc + s4, texc + s5, texc + s6};
        ((int4*)(off + base))[0] = o0;
        ((int4*)(off + base))[1] = o1;
    }
}

__global__ void k_scatter64(const int* __restrict__ dst, const int* __restrict__ src,
                            const int* __restrict__ off, int* __restrict__ cur,
                            unsigned long long* __restrict__ code64) {
    int e = blockIdx.x * blockDim.x + threadIdx.x;
    if (e < N_EDGES) {
        int d = dst[e];
        int p = off[d] + atomicAdd(&cur[d], 1);
        code64[p] = ((unsigned long long)(unsigned)src[e] << 32) | (unsigned)e;
    }
}

__global__ void k_scatter32(const int* __restrict__ dst, const int* __restrict__ off,
                            int* __restrict__ cur, int* __restrict__ eid) {
    int e = blockIdx.x * blockDim.x + threadIdx.x;
    if (e < N_EDGES) {
        int d = dst[e];
        int p = off[d] + atomicAdd(&cur[d], 1);
        eid[p] = e;
    }
}

// ---------------- weight fold: Wc = Wa_N @ Wm, bc = Wa_N @ bm + ba ----------------
__global__ void k_prec(const float* __restrict__ Wm, const float* __restrict__ bm,
                       const float* __restrict__ Wa, const float* __restrict__ ba,
                       float* __restrict__ Wc, float* __restrict__ bc) {
    int o = blockIdx.x;       // 64
    int k = threadIdx.x;      // 128
    const float* war = Wa + o * 128 + 64;
    float s = 0.f;
    #pragma unroll 8
    for (int j = 0; j < 64; j++) s += war[j] * Wm[j * 128 + k];
    Wc[o * 128 + k] = s;
    if (k == 0) {
        float t = ba[o];
        for (int j = 0; j < 64; j++) t += war[j] * bm[j];
        bc[o] = t;
    }
}

// ---------------- wave-per-node aggregation (writes MEAN) ----------------
__device__ __forceinline__ float4 ld_feat(const float* __restrict__ nf,
                                          const float* __restrict__ ef,
                                          unsigned long long c, int slot) {
    unsigned e = (unsigned)c;
    unsigned sv = (unsigned)(c >> 32);
    const float* p = (slot < 16) ? (nf + (size_t)sv * 64 + slot * 4)
                                 : (ef + (size_t)e * 64 + (slot - 16) * 4);
    return *(const float4*)p;
}

__global__ __launch_bounds__(256) void k_agg(
    const float* __restrict__ nf, const float* __restrict__ ef,
    const int* __restrict__ cnt, const int* __restrict__ off,
    const unsigned long long* __restrict__ code64, float* __restrict__ aggG) {
    int tid = threadIdx.x, lane = tid & 63, wid = tid >> 6;
    int n = blockIdx.x * 4 + wid;
    if (n >= N_NODES) return;
    int slot = lane & 31, half = lane >> 5;
    int st = off[n], deg = cnt[n];
    int pend = st + deg;
    float4 acc = make_float4(0.f, 0.f, 0.f, 0.f);
    int p = st + half;
    for (; p + 6 < pend; p += 8) {
        unsigned long long c0 = code64[p];
        unsigned long long c1 = code64[p + 2];
        unsigned long long c2 = code64[p + 4];
        unsigned long long c3 = code64[p + 6];
        float4 a0 = ld_feat(nf, ef, c0, slot);
        float4 a1 = ld_feat(nf, ef, c1, slot);
        float4 a2 = ld_feat(nf, ef, c2, slot);
        float4 a3 = ld_feat(nf, ef, c3, slot);
        acc.x += a0.x + a1.x + a2.x + a3.x;
        acc.y += a0.y + a1.y + a2.y + a3.y;
        acc.z += a0.z + a1.z + a2.z + a3.z;
        acc.w += a0.w + a1.w + a2.w + a3.w;
    }
    for (; p < pend; p += 2) {
        unsigned long long c = code64[p];
        float4 a = ld_feat(nf, ef, c, slot);
        acc.x += a.x; acc.y += a.y; acc.z += a.z; acc.w += a.w;
    }
    acc.x += __shfl_xor(acc.x, 32, 64);
    acc.y += __shfl_xor(acc.y, 32, 64);
    acc.z += __shfl_xor(acc.z, 32, 64);
    acc.w += __shfl_xor(acc.w, 32, 64);
    if (half == 0) {
        float inv = (deg > 0) ? 1.f / (float)deg : 0.f;
        acc.x *= inv; acc.y *= inv; acc.z *= inv; acc.w *= inv;
        *(float4*)(aggG + (size_t)n * 128 + slot * 4) = acc;
    }
}

// ---------------- apply: out = relu(WaH @ h + Wc @ mean + bias) ----------------
// 256 threads, 64 nodes/block. BOTH operand tiles staged in LDS (h + mean),
// so the inner GEMM loops touch only LDS + L1-hot weights -> issue-bound.
// LDS ~52 KB -> 3 blocks/CU; plain launch_bounds (r4's ",4" caused VGPR=64
// + massive scratch spill traffic: 562 MB HBM, 266 us).
__global__ __launch_bounds__(256) void k_apply(
    const float* __restrict__ nf, const float* __restrict__ aggG,
    const int* __restrict__ cnt,
    const float* __restrict__ Wa, const float* __restrict__ Wc,
    const float* __restrict__ ba, const float* __restrict__ bc,
    float* __restrict__ out) {
    __shared__ __align__(16) float am[64][132];
    __shared__ __align__(16) float hf[64][68];
    __shared__ float degl[64];

    int tid = threadIdx.x;
    int base = blockIdx.x * 64;

    // stage mean tile (64 x 128) coalesced
    {
        const float4* g4 = (const float4*)aggG;
        #pragma unroll
        for (int r = 0; r < 8; r++) {
            int f = r * 256 + tid;   // 0..2047
            int row = f >> 5, c4 = f & 31;
            float4 v = make_float4(0.f, 0.f, 0.f, 0.f);
            if (base + row < N_NODES) v = g4[(size_t)(base + row) * 32 + c4];
            *(float4*)&am[row][c4 * 4] = v;
        }
        // stage h tile (64 x 64) coalesced
        const float4* n4 = (const float4*)nf;
        #pragma unroll
        for (int r = 0; r < 4; r++) {
            int f = r * 256 + tid;   // 0..1023
            int row = f >> 4, c4 = f & 15;
            float4 v = make_float4(0.f, 0.f, 0.f, 0.f);
            if (base + row < N_NODES) v = n4[(size_t)(base + row) * 16 + c4];
            *(float4*)&hf[row][c4 * 4] = v;
        }
        if (tid < 64) degl[tid] = (base + tid < N_NODES) ? (float)cnt[base + tid] : 0.f;
    }
    __syncthreads();

    int og = (tid & 15) * 4;
    int ng = (tid >> 4) * 4;
    float acc[4][4] = {};
    const float4* Wa4 = (const float4*)Wa;  // row o = 32 float4, first 16 = h-part
    const float4* Wc4 = (const float4*)Wc;  // row o = 32 float4

    // part 1: h from LDS
    #pragma unroll 4
    for (int k4 = 0; k4 < 16; k4++) {
        float4 hv[4], wv[4];
        #pragma unroll
        for (int i = 0; i < 4; i++) hv[i] = *(const float4*)&hf[ng + i][k4 * 4];
        #pragma unroll
        for (int j = 0; j < 4; j++) wv[j] = Wa4[(og + j) * 32 + k4];
        #pragma unroll
        for (int i = 0; i < 4; i++)
            #pragma unroll
            for (int j = 0; j < 4; j++)
                acc[i][j] += hv[i].x * wv[j].x + hv[i].y * wv[j].y +
                             hv[i].z * wv[j].z + hv[i].w * wv[j].w;
    }
    // part 2: mean from LDS
    #pragma unroll 4
    for (int k4 = 0; k4 < 32; k4++) {
        float4 av[4], wv[4];
        #pragma unroll
        for (int i = 0; i < 4; i++) av[i] = *(const float4*)&am[ng + i][k4 * 4];
        #pragma unroll
        for (int j = 0; j < 4; j++) wv[j] = Wc4[(og + j) * 32 + k4];
        #pragma unroll
        for (int i = 0; i < 4; i++)
            #pragma unroll
            for (int j = 0; j < 4; j++)
                acc[i][j] += av[i].x * wv[j].x + av[i].y * wv[j].y +
                             av[i].z * wv[j].z + av[i].w * wv[j].w;
    }
    // epilogue: bias select + relu
    #pragma unroll
    for (int i = 0; i < 4; i++) {
        int n = base + ng + i;
        if (n < N_NODES) {
            float d = degl[ng + i];
            float4 o;
            o.x = fmaxf(acc[i][0] + ((d > 0.f) ? bc[og + 0] : ba[og + 0]), 0.f);
            o.y = fmaxf(acc[i][1] + ((d > 0.f) ? bc[og + 1] : ba[og + 1]), 0.f);
            o.z = fmaxf(acc[i][2] + ((d > 0.f) ? bc[og + 2] : ba[og + 2]), 0.f);
            o.w = fmaxf(acc[i][3] + ((d > 0.f) ? bc[og + 3] : ba[og + 3]), 0.f);
            *(float4*)&out[(size_t)n * 64 + og] = o;
        }
    }
}

// ---------------- fallback (round-1 kernel, known good) ----------------
__global__ __launch_bounds__(256) void k_node_fb(
    const float* __restrict__ nf, const float* __restrict__ ef,
    const int* __restrict__ src, const int* __restrict__ cnt,
    const int* __restrict__ off, const int* __restrict__ eid,
    const float* __restrict__ Wm, const float* __restrict__ bm,
    const float* __restrict__ Wa, const float* __restrict__ ba,
    float* __restrict__ out) {
    __shared__ __align__(16) float agg[64][132];
    __shared__ __align__(16) float hn[64][68];
    __shared__ float degl[64];

    int tid = threadIdx.x, lane = tid & 63, wid = tid >> 6;
    int base = blockIdx.x * 64;

    for (int q = 0; q < 16; q++) {
        int nl = wid * 16 + q;
        int n = base + nl;
        float sh = 0.f, se = 0.f;
        int dg = 0;
        if (n < N_NODES) {
            dg = cnt[n];
            int st = off[n];
            for (int c0 = 0; c0 < dg; c0 += 64) {
                int m = dg - c0;
                if (m > 64) m = 64;
                int e_l = 0, s_l = 0;
                if (lane < m) {
                    e_l = eid[st + c0 + lane];
                    s_l = src[e_l];
                }
                for (int j = 0; j < m; j++) {
                    int e = __shfl(e_l, j, 64);
                    int s = __shfl(s_l, j, 64);
                    sh += nf[(size_t)s * 64 + lane];
                    se += ef[(size_t)e * 64 + lane];
                }
            }
        }
        agg[nl][lane] = sh;
        agg[nl][64 + lane] = se;
        if (lane == 0) degl[nl] = (float)dg;
    }
    __syncthreads();

    int og = (tid & 15) * 4;
    int ng = (tid >> 4) * 4;
    float acc[4][4] = {};
    const float4* Wm4 = (const float4*)Wm;
    #pragma unroll 4
    for (int k4 = 0; k4 < 32; k4++) {
        float4 av[4], wv[4];
        #pragma unroll
        for (int i = 0; i < 4; i++) av[i] = *(const float4*)&agg[ng + i][k4 * 4];
        #pragma unroll
        for (int j = 0; j < 4; j++) wv[j] = Wm4[(og + j) * 32 + k4];
        #pragma unroll
        for (int i = 0; i < 4; i++)
            #pragma unroll
            for (int j = 0; j < 4; j++)
                acc[i][j] += av[i].x * wv[j].x + av[i].y * wv[j].y +
                             av[i].z * wv[j].z + av[i].w * wv[j].w;
    }
    #pragma unroll
    for (int i = 0; i < 4; i++) {
        float d = degl[ng + i];
        float inv = (d > 0.f) ? 1.f / d : 0.f;
        #pragma unroll
        for (int j = 0; j < 4; j++) {
            float v = (d > 0.f) ? acc[i][j] * inv + bm[og + j] : 0.f;
            hn[ng + i][og + j] = v;
        }
    }
    __syncthreads();

    float acc2[4][4] = {};
    const float4* Wa4 = (const float4*)Wa;
    #pragma unroll 4
    for (int k4 = 0; k4 < 16; k4++) {
        float4 hv[4], wv[4];
        #pragma unroll
        for (int i = 0; i < 4; i++) {
            int n = base + ng + i;
            if (n < N_NODES)
                hv[i] = ((const float4*)(nf + (size_t)n * 64))[k4];
            else
                hv[i] = make_float4(0.f, 0.f, 0.f, 0.f);
        }
        #pragma unroll
        for (int j = 0; j < 4; j++) wv[j] = Wa4[(og + j) * 32 + k4];
        #pragma unroll
        for (int i = 0; i < 4; i++)
            #pragma unroll
            for (int j = 0; j < 4; j++)
                acc2[i][j] += hv[i].x * wv[j].x + hv[i].y * wv[j].y +
                              hv[i].z * wv[j].z + hv[i].w * wv[j].w;
    }
    #pragma unroll 4
    for (int k4 = 0; k4 < 16; k4++) {
        float4 hv[4], wv[4];
        #pragma unroll
        for (int i = 0; i < 4; i++) hv[i] = *(const float4*)&hn[ng + i][k4 * 4];
        #pragma unroll
        for (int j = 0; j < 4; j++) wv[j] = Wa4[(og + j) * 32 + 16 + k4];
        #pragma unroll
        for (int i = 0; i < 4; i++)
            #pragma unroll
            for (int j = 0; j < 4; j++)
                acc2[i][j] += hv[i].x * wv[j].x + hv[i].y * wv[j].y +
                              hv[i].z * wv[j].z + hv[i].w * wv[j].w;
    }
    #pragma unroll
    for (int i = 0; i < 4; i++) {
        int n = base + ng + i;
        if (n < N_NODES) {
            float4 o;
            o.x = fmaxf(acc2[i][0] + ba[og + 0], 0.f);
            o.y = fmaxf(acc2[i][1] + ba[og + 1], 0.f);
            o.z = fmaxf(acc2[i][2] + ba[og + 2], 0.f);
            o.w = fmaxf(acc2[i][3] + ba[og + 3], 0.f);
            *(float4*)&out[(size_t)n * 64 + og] = o;
        }
    }
}

extern "C" void kernel_launch(void* const* d_in, const int* in_sizes, int n_in,
                              void* d_out, int out_size, void* d_ws, size_t ws_size,
                              hipStream_t stream) {
    const float* nf = (const float*)d_in[0];
    const float* ef = (const float*)d_in[1];
    const int* src = (const int*)d_in[2];
    const int* dst = (const int*)d_in[3];
    const float* Wm = (const float*)d_in[4];
    const float* bm = (const float*)d_in[5];
    const float* Wa = (const float*)d_in[6];
    const float* ba = (const float*)d_in[7];
    float* out = (float*)d_out;

    // ws layout: cnt[N], cur[N], part[64] (zeroed), off[N], code64[E], aggG[N*128], Wc[64*128], bc[64]
    int* cnt = (int*)d_ws;
    int* cur = cnt + N_NODES;
    int* part = cur + N_NODES;
    int* off = part + 64;
    size_t csr_bytes = (size_t)(3 * N_NODES + 64) * 4;  // 1,200,256 B (8B-aligned)

    int nz = 2 * N_NODES + 64;  // cnt, cur, part
    k_zero<<<(nz + 255) / 256, 256, 0, stream>>>(cnt, nz);
    k_count<<<(N_EDGES + 255) / 256, 256, 0, stream>>>(dst, cnt);
    k_partial<<<NB_SCAN, 256, 0, stream>>>(cnt, part);
    k_scan_part<<<1, 64, 0, stream>>>(part, NB_SCAN);
    k_scan_chunks<<<NB_SCAN, 256, 0, stream>>>(cnt, part, off);

    size_t need = csr_bytes + (size_t)N_EDGES * 8 + (size_t)N_NODES * 128 * 4 +
                  (size_t)64 * 128 * 4 + 256;
    if (ws_size >= need) {
        unsigned long long* code64 = (unsigned long long*)((char*)d_ws + csr_bytes);
        float* aggG = (float*)((char*)code64 + (size_t)N_EDGES * 8);
        float* Wc = aggG + (size_t)N_NODES * 128;
        float* bc = Wc + 64 * 128;
        k_prec<<<64, 128, 0, stream>>>(Wm, bm, Wa, ba, Wc, bc);
        k_scatter64<<<(N_EDGES + 255) / 256, 256, 0, stream>>>(dst, src, off, cur, code64);
        k_agg<<<N_NODES / 4, 256, 0, stream>>>(nf, ef, cnt, off, code64, aggG);
        k_apply<<<(N_NODES + 63) / 64, 256, 0, stream>>>(nf, aggG, cnt, Wa, Wc, ba, bc, out);
    } else {
        int* eid = (int*)((char*)d_ws + csr_bytes);
        k_scatter32<<<(N_EDGES + 255) / 256, 256, 0, stream>>>(dst, off, cur, eid);
        k_node_fb<<<(N_NODES + 63) / 64, 256, 0, stream>>>(nf, ef, src, cnt, off, eid,
                                                           Wm, bm, Wa, ba, out);
    }
}

// Round 6
// 315.871 us; speedup vs baseline: 1.7551x; 1.4422x over previous
//
#include <hip/hip_runtime.h>

#define N_NODES 100000
#define N_EDGES 1600000
#define NB_SCAN 49  // ceil(100000/2048)

typedef __attribute__((ext_vector_type(8))) short bf16x8;
typedef __attribute__((ext_vector_type(4))) float f32x4;

// ---------------- CSR build ----------------

__global__ void k_zero(int* __restrict__ p, int n) {
    int i = blockIdx.x * blockDim.x + threadIdx.x;
    if (i < n) p[i] = 0;
}

__global__ void k_count(const int* __restrict__ dst, int* __restrict__ cnt) {
    int e = blockIdx.x * blockDim.x + threadIdx.x;
    if (e < N_EDGES) atomicAdd(&cnt[dst[e]], 1);
}

__global__ void k_partial(const int* __restrict__ cnt, int* __restrict__ part) {
    __shared__ int red[256];
    int t = threadIdx.x;
    int base = blockIdx.x * 2048 + t * 8;
    int s = 0;
    if (base < N_NODES) {  // N_NODES % 8 == 0
        const int4* p = (const int4*)(cnt + base);
        int4 a = p[0], b = p[1];
        s = a.x + a.y + a.z + a.w + b.x + b.y + b.z + b.w;
    }
    red[t] = s;
    __syncthreads();
    for (int d = 128; d > 0; d >>= 1) {
        if (t < d) red[t] += red[t + d];
        __syncthreads();
    }
    if (t == 0) part[blockIdx.x] = red[0];
}

__global__ void k_scan_part(int* __restrict__ part, int nb) {
    int lane = threadIdx.x;
    int v = (lane < nb) ? part[lane] : 0;
    int incl = v;
    #pragma unroll
    for (int d = 1; d < 64; d <<= 1) {
        int u = __shfl_up(incl, d, 64);
        if (lane >= d) incl += u;
    }
    if (lane < nb) part[lane] = incl - v;
}

__global__ void k_scan_chunks(const int* __restrict__ cnt, const int* __restrict__ part,
                              int* __restrict__ off) {
    __shared__ int wtot[4];
    __shared__ int wexc[4];
    int t = threadIdx.x, b = blockIdx.x;
    int base = b * 2048 + t * 8;
    int4 a = {0, 0, 0, 0}, c = {0, 0, 0, 0};
    if (base < N_NODES) {
        const int4* p = (const int4*)(cnt + base);
        a = p[0];
        c = p[1];
    }
    int s0 = a.x, s1 = s0 + a.y, s2 = s1 + a.z, s3 = s2 + a.w;
    int s4 = s3 + c.x, s5 = s4 + c.y, s6 = s5 + c.z, s7 = s6 + c.w;
    int tot = s7;
    int lane = t & 63, wid = t >> 6;
    int incl = tot;
    #pragma unroll
    for (int d = 1; d < 64; d <<= 1) {
        int u = __shfl_up(incl, d, 64);
        if (lane >= d) incl += u;
    }
    if (lane == 63) wtot[wid] = incl;
    __syncthreads();
    if (t == 0) {
        int r = 0;
        for (int i = 0; i < 4; i++) { int v = wtot[i]; wexc[i] = r; r += v; }
    }
    __syncthreads();
    int texc = incl - tot + wexc[wid] + part[b];
    if (base < N_NODES) {
        int4 o0 = {texc, texc + s0, texc + s1, texc + s2};
        int4 o1 = {texc + s3, texc + s4, texc + s5, texc + s6};
        ((int4*)(off + base))[0] = o0;
        ((int4*)(off + base))[1] = o1;
    }
}

__global__ void k_scatter64(const int* __restrict__ dst, const int* __restrict__ src,
                            const int* __restrict__ off, int* __restrict__ cur,
                            unsigned long long* __restrict__ code64) {
    int e = blockIdx.x * blockDim.x + threadIdx.x;
    if (e < N_EDGES) {
        int d = dst[e];
        int p = off[d] + atomicAdd(&cur[d], 1);
        code64[p] = ((unsigned long long)(unsigned)src[e] << 32) | (unsigned)e;
    }
}

__global__ void k_scatter32(const int* __restrict__ dst, const int* __restrict__ off,
                            int* __restrict__ cur, int* __restrict__ eid) {
    int e = blockIdx.x * blockDim.x + threadIdx.x;
    if (e < N_EDGES) {
        int d = dst[e];
        int p = off[d] + atomicAdd(&cur[d], 1);
        eid[p] = e;
    }
}

// ---------------- weight fold -> bf16 fused weight Wf[o][0..191] ----------------
// Wf[o][k<64] = Wa[o][k] (h part); Wf[o][64+m] = sum_j Wa[o][64+j]*Wm[j][m].
// bc[o] = ba[o] + sum_j Wa[o][64+j]*bm[j].
__device__ __forceinline__ unsigned short f2bf(float f) {
    unsigned u = __float_as_uint(f);
    return (unsigned short)((u + 0x7FFFu + ((u >> 16) & 1u)) >> 16);
}

__global__ void k_prec(const float* __restrict__ Wm, const float* __restrict__ bm,
                       const float* __restrict__ Wa, const float* __restrict__ ba,
                       unsigned short* __restrict__ Wf, float* __restrict__ bc) {
    int o = blockIdx.x;       // 64
    int k = threadIdx.x;      // 192
    const float* war = Wa + o * 128 + 64;
    float w;
    if (k < 64) {
        w = Wa[o * 128 + k];
    } else {
        int m = k - 64;
        float s = 0.f;
        #pragma unroll 8
        for (int j = 0; j < 64; j++) s += war[j] * Wm[j * 128 + m];
        w = s;
    }
    Wf[o * 192 + k] = f2bf(w);
    if (k == 0) {
        float t = ba[o];
        for (int j = 0; j < 64; j++) t += war[j] * bm[j];
        bc[o] = t;
    }
}

// ---------------- wave-per-node aggregation (writes MEAN, fp32) ----------------
__device__ __forceinline__ float4 ld_feat(const float* __restrict__ nf,
                                          const float* __restrict__ ef,
                                          unsigned long long c, int slot) {
    unsigned e = (unsigned)c;
    unsigned sv = (unsigned)(c >> 32);
    const float* p = (slot < 16) ? (nf + (size_t)sv * 64 + slot * 4)
                                 : (ef + (size_t)e * 64 + (slot - 16) * 4);
    return *(const float4*)p;
}

__global__ __launch_bounds__(256) void k_agg(
    const float* __restrict__ nf, const float* __restrict__ ef,
    const int* __restrict__ cnt, const int* __restrict__ off,
    const unsigned long long* __restrict__ code64, float* __restrict__ aggG) {
    int tid = threadIdx.x, lane = tid & 63, wid = tid >> 6;
    int n = blockIdx.x * 4 + wid;
    if (n >= N_NODES) return;
    int slot = lane & 31, half = lane >> 5;
    int st = off[n], deg = cnt[n];
    int pend = st + deg;
    float4 acc = make_float4(0.f, 0.f, 0.f, 0.f);
    int p = st + half;
    for (; p + 6 < pend; p += 8) {
        unsigned long long c0 = code64[p];
        unsigned long long c1 = code64[p + 2];
        unsigned long long c2 = code64[p + 4];
        unsigned long long c3 = code64[p + 6];
        float4 a0 = ld_feat(nf, ef, c0, slot);
        float4 a1 = ld_feat(nf, ef, c1, slot);
        float4 a2 = ld_feat(nf, ef, c2, slot);
        float4 a3 = ld_feat(nf, ef, c3, slot);
        acc.x += a0.x + a1.x + a2.x + a3.x;
        acc.y += a0.y + a1.y + a2.y + a3.y;
        acc.z += a0.z + a1.z + a2.z + a3.z;
        acc.w += a0.w + a1.w + a2.w + a3.w;
    }
    for (; p < pend; p += 2) {
        unsigned long long c = code64[p];
        float4 a = ld_feat(nf, ef, c, slot);
        acc.x += a.x; acc.y += a.y; acc.z += a.z; acc.w += a.w;
    }
    acc.x += __shfl_xor(acc.x, 32, 64);
    acc.y += __shfl_xor(acc.y, 32, 64);
    acc.z += __shfl_xor(acc.z, 32, 64);
    acc.w += __shfl_xor(acc.w, 32, 64);
    if (half == 0) {
        float inv = (deg > 0) ? 1.f / (float)deg : 0.f;
        acc.x *= inv; acc.y *= inv; acc.z *= inv; acc.w *= inv;
        *(float4*)(aggG + (size_t)n * 128 + slot * 4) = acc;
    }
}

// ---------------- apply via MFMA: out = relu([h|mean] @ Wf^T + bias) ----------------
// 256 thr / 64 nodes. Stage cat[64][192->200] bf16 (h||mean) + wt[64][192->200]
// bf16 in LDS; 4 waves x (6 A-frag ds_reads + 24 B-frag + 24 mfma_16x16x32_bf16).
// Replaces the FMA k_apply whose weight loads cost 16 L1-lines/instr.
__device__ __forceinline__ void st_bf4(unsigned short* p, float4 v) {
    unsigned lo = (unsigned)f2bf(v.x) | ((unsigned)f2bf(v.y) << 16);
    unsigned hi = (unsigned)f2bf(v.z) | ((unsigned)f2bf(v.w) << 16);
    uint2 u = {lo, hi};
    *(uint2*)p = u;
}

__global__ __launch_bounds__(256) void k_apply_mfma(
    const float* __restrict__ nf, const float* __restrict__ aggG,
    const int* __restrict__ cnt, const unsigned short* __restrict__ Wf,
    const float* __restrict__ ba, const float* __restrict__ bc,
    float* __restrict__ out) {
    __shared__ __align__(16) unsigned short cat[64][200];  // stride 400 B
    __shared__ __align__(16) unsigned short wt[64][200];
    __shared__ float degl[64];

    int tid = threadIdx.x;
    int base = blockIdx.x * 64;

    // stage weights (64x192 bf16 = 6144 dwords, coalesced)
    {
        const unsigned* Wfu = (const unsigned*)Wf;
        #pragma unroll
        for (int r = 0; r < 24; r++) {
            int u = r * 256 + tid;     // 0..6143
            int o = u / 96;            // 96 dwords per row
            int c = u - o * 96;
            *(unsigned*)&wt[o][2 * c] = Wfu[u];
        }
    }
    // stage h -> cat[:,0:64)
    {
        const float4* n4 = (const float4*)nf;
        #pragma unroll
        for (int r = 0; r < 4; r++) {
            int f = r * 256 + tid;     // 0..1023
            int nl = f >> 4, c4 = f & 15;
            float4 v = make_float4(0.f, 0.f, 0.f, 0.f);
            if (base + nl < N_NODES) v = n4[(size_t)(base + nl) * 16 + c4];
            st_bf4(&cat[nl][c4 * 4], v);
        }
    }
    // stage mean -> cat[:,64:192)
    {
        const float4* g4 = (const float4*)aggG;
        #pragma unroll
        for (int r = 0; r < 8; r++) {
            int f = r * 256 + tid;     // 0..2047
            int nl = f >> 5, c4 = f & 31;
            float4 v = make_float4(0.f, 0.f, 0.f, 0.f);
            if (base + nl < N_NODES) v = g4[(size_t)(base + nl) * 32 + c4];
            st_bf4(&cat[nl][64 + c4 * 4], v);
        }
    }
    if (tid < 64) degl[tid] = (base + tid < N_NODES) ? (float)cnt[base + tid] : 0.f;
    __syncthreads();

    int lane = tid & 63, w = tid >> 6;
    int sn = w * 16;              // this wave's 16-node slice
    int lr = lane & 15;           // A: row (node); B: col (output)
    int lg = lane >> 4;           // k-group (8 bf16 each)

    // A fragments: cat[sn+lr][ks*32 + lg*8 .. +8]
    bf16x8 a[6];
    #pragma unroll
    for (int ks = 0; ks < 6; ks++)
        a[ks] = *(const bf16x8*)&cat[sn + lr][ks * 32 + lg * 8];

    float degv[4];
    #pragma unroll
    for (int r = 0; r < 4; r++) degv[r] = degl[sn + lg * 4 + r];

    #pragma unroll
    for (int cb = 0; cb < 4; cb++) {
        f32x4 acc = {0.f, 0.f, 0.f, 0.f};
        #pragma unroll
        for (int ks = 0; ks < 6; ks++) {
            bf16x8 b = *(const bf16x8*)&wt[cb * 16 + lr][ks * 32 + lg * 8];
            acc = __builtin_amdgcn_mfma_f32_16x16x32_bf16(a[ks], b, acc, 0, 0, 0);
        }
        int o = cb * 16 + lr;
        float bcv = bc[o], bav = ba[o];
        // C/D: col=lane&15 (=output o), row=(lane>>4)*4+r (=node in slice)
        #pragma unroll
        for (int r = 0; r < 4; r++) {
            int n = base + sn + lg * 4 + r;
            if (n < N_NODES) {
                float v = acc[r] + ((degv[r] > 0.f) ? bcv : bav);
                out[(size_t)n * 64 + o] = fmaxf(v, 0.f);
            }
        }
    }
}

// ---------------- fallback (round-1 kernel, known good) ----------------
__global__ __launch_bounds__(256) void k_node_fb(
    const float* __restrict__ nf, const float* __restrict__ ef,
    const int* __restrict__ src, const int* __restrict__ cnt,
    const int* __restrict__ off, const int* __restrict__ eid,
    const float* __restrict__ Wm, const float* __restrict__ bm,
    const float* __restrict__ Wa, const float* __restrict__ ba,
    float* __restrict__ out) {
    __shared__ __align__(16) float agg[64][132];
    __shared__ __align__(16) float hn[64][68];
    __shared__ float degl[64];

    int tid = threadIdx.x, lane = tid & 63, wid = tid >> 6;
    int base = blockIdx.x * 64;

    for (int q = 0; q < 16; q++) {
        int nl = wid * 16 + q;
        int n = base + nl;
        float sh = 0.f, se = 0.f;
        int dg = 0;
        if (n < N_NODES) {
            dg = cnt[n];
            int st = off[n];
            for (int c0 = 0; c0 < dg; c0 += 64) {
                int m = dg - c0;
                if (m > 64) m = 64;
                int e_l = 0, s_l = 0;
                if (lane < m) {
                    e_l = eid[st + c0 + lane];
                    s_l = src[e_l];
                }
                for (int j = 0; j < m; j++) {
                    int e = __shfl(e_l, j, 64);
                    int s = __shfl(s_l, j, 64);
                    sh += nf[(size_t)s * 64 + lane];
                    se += ef[(size_t)e * 64 + lane];
                }
            }
        }
        agg[nl][lane] = sh;
        agg[nl][64 + lane] = se;
        if (lane == 0) degl[nl] = (float)dg;
    }
    __syncthreads();

    int og = (tid & 15) * 4;
    int ng = (tid >> 4) * 4;
    float acc[4][4] = {};
    const float4* Wm4 = (const float4*)Wm;
    #pragma unroll 4
    for (int k4 = 0; k4 < 32; k4++) {
        float4 av[4], wv[4];
        #pragma unroll
        for (int i = 0; i < 4; i++) av[i] = *(const float4*)&agg[ng + i][k4 * 4];
        #pragma unroll
        for (int j = 0; j < 4; j++) wv[j] = Wm4[(og + j) * 32 + k4];
        #pragma unroll
        for (int i = 0; i < 4; i++)
            #pragma unroll
            for (int j = 0; j < 4; j++)
                acc[i][j] += av[i].x * wv[j].x + av[i].y * wv[j].y +
                             av[i].z * wv[j].z + av[i].w * wv[j].w;
    }
    #pragma unroll
    for (int i = 0; i < 4; i++) {
        float d = degl[ng + i];
        float inv = (d > 0.f) ? 1.f / d : 0.f;
        #pragma unroll
        for (int j = 0; j < 4; j++) {
            float v = (d > 0.f) ? acc[i][j] * inv + bm[og + j] : 0.f;
            hn[ng + i][og + j] = v;
        }
    }
    __syncthreads();

    float acc2[4][4] = {};
    const float4* Wa4 = (const float4*)Wa;
    #pragma unroll 4
    for (int k4 = 0; k4 < 16; k4++) {
        float4 hv[4], wv[4];
        #pragma unroll
        for (int i = 0; i < 4; i++) {
            int n = base + ng + i;
            if (n < N_NODES)
                hv[i] = ((const float4*)(nf + (size_t)n * 64))[k4];
            else
                hv[i] = make_float4(0.f, 0.f, 0.f, 0.f);
        }
        #pragma unroll
        for (int j = 0; j < 4; j++) wv[j] = Wa4[(og + j) * 32 + k4];
        #pragma unroll
        for (int i = 0; i < 4; i++)
            #pragma unroll
            for (int j = 0; j < 4; j++)
                acc2[i][j] += hv[i].x * wv[j].x + hv[i].y * wv[j].y +
                              hv[i].z * wv[j].z + hv[i].w * wv[j].w;
    }
    #pragma unroll 4
    for (int k4 = 0; k4 < 16; k4++) {
        float4 hv[4], wv[4];
        #pragma unroll
        for (int i = 0; i < 4; i++) hv[i] = *(const float4*)&hn[ng + i][k4 * 4];
        #pragma unroll
        for (int j = 0; j < 4; j++) wv[j] = Wa4[(og + j) * 32 + 16 + k4];
        #pragma unroll
        for (int i = 0; i < 4; i++)
            #pragma unroll
            for (int j = 0; j < 4; j++)
                acc2[i][j] += hv[i].x * wv[j].x + hv[i].y * wv[j].y +
                              hv[i].z * wv[j].z + hv[i].w * wv[j].w;
    }
    #pragma unroll
    for (int i = 0; i < 4; i++) {
        int n = base + ng + i;
        if (n < N_NODES) {
            float4 o;
            o.x = fmaxf(acc2[i][0] + ba[og + 0], 0.f);
            o.y = fmaxf(acc2[i][1] + ba[og + 1], 0.f);
            o.z = fmaxf(acc2[i][2] + ba[og + 2], 0.f);
            o.w = fmaxf(acc2[i][3] + ba[og + 3], 0.f);
            *(float4*)&out[(size_t)n * 64 + og] = o;
        }
    }
}

extern "C" void kernel_launch(void* const* d_in, const int* in_sizes, int n_in,
                              void* d_out, int out_size, void* d_ws, size_t ws_size,
                              hipStream_t stream) {
    const float* nf = (const float*)d_in[0];
    const float* ef = (const float*)d_in[1];
    const int* src = (const int*)d_in[2];
    const int* dst = (const int*)d_in[3];
    const float* Wm = (const float*)d_in[4];
    const float* bm = (const float*)d_in[5];
    const float* Wa = (const float*)d_in[6];
    const float* ba = (const float*)d_in[7];
    float* out = (float*)d_out;

    // ws layout: cnt[N], cur[N], part[64] (zeroed), off[N], code64[E],
    //            aggG[N*128] f32, Wf[64*192] bf16, bc[64] f32
    int* cnt = (int*)d_ws;
    int* cur = cnt + N_NODES;
    int* part = cur + N_NODES;
    int* off = part + 64;
    size_t csr_bytes = (size_t)(3 * N_NODES + 64) * 4;  // 8B-aligned

    int nz = 2 * N_NODES + 64;  // cnt, cur, part
    k_zero<<<(nz + 255) / 256, 256, 0, stream>>>(cnt, nz);
    k_count<<<(N_EDGES + 255) / 256, 256, 0, stream>>>(dst, cnt);
    k_partial<<<NB_SCAN, 256, 0, stream>>>(cnt, part);
    k_scan_part<<<1, 64, 0, stream>>>(part, NB_SCAN);
    k_scan_chunks<<<NB_SCAN, 256, 0, stream>>>(cnt, part, off);

    size_t need = csr_bytes + (size_t)N_EDGES * 8 + (size_t)N_NODES * 128 * 4 +
                  (size_t)64 * 192 * 2 + 512;
    if (ws_size >= need) {
        unsigned long long* code64 = (unsigned long long*)((char*)d_ws + csr_bytes);
        float* aggG = (float*)((char*)code64 + (size_t)N_EDGES * 8);
        unsigned short* Wf = (unsigned short*)(aggG + (size_t)N_NODES * 128);
        float* bc = (float*)(Wf + 64 * 192);
        k_prec<<<64, 192, 0, stream>>>(Wm, bm, Wa, ba, Wf, bc);
        k_scatter64<<<(N_EDGES + 255) / 256, 256, 0, stream>>>(dst, src, off, cur, code64);
        k_agg<<<N_NODES / 4, 256, 0, stream>>>(nf, ef, cnt, off, code64, aggG);
        k_apply_mfma<<<(N_NODES + 63) / 64, 256, 0, stream>>>(nf, aggG, cnt, Wf, ba, bc, out);
    } else {
        int* eid = (int*)((char*)d_ws + csr_bytes);
        k_scatter32<<<(N_EDGES + 255) / 256, 256, 0, stream>>>(dst, off, cur, eid);
        k_node_fb<<<(N_NODES + 63) / 64, 256, 0, stream>>>(nf, ef, src, cnt, off, eid,
                                                           Wm, bm, Wa, ba, out);
    }
}

// Round 7
// 307.592 us; speedup vs baseline: 1.8023x; 1.0269x over previous
//
#include <hip/hip_runtime.h>

#define N_NODES 100000
#define N_EDGES 1600000
#define NB_SCAN 49  // ceil(100000/2048)

typedef __attribute__((ext_vector_type(8))) short bf16x8;
typedef __attribute__((ext_vector_type(4))) float f32x4;

// ---------------- CSR build ----------------

__global__ void k_zero(int* __restrict__ p, int n) {
    int i = blockIdx.x * blockDim.x + threadIdx.x;
    if (i < n) p[i] = 0;
}

__global__ void k_count(const int* __restrict__ dst, int* __restrict__ cnt) {
    int e = blockIdx.x * blockDim.x + threadIdx.x;
    if (e < N_EDGES) atomicAdd(&cnt[dst[e]], 1);
}

__global__ void k_partial(const int* __restrict__ cnt, int* __restrict__ part) {
    __shared__ int red[256];
    int t = threadIdx.x;
    int base = blockIdx.x * 2048 + t * 8;
    int s = 0;
    if (base < N_NODES) {  // N_NODES % 8 == 0
        const int4* p = (const int4*)(cnt + base);
        int4 a = p[0], b = p[1];
        s = a.x + a.y + a.z + a.w + b.x + b.y + b.z + b.w;
    }
    red[t] = s;
    __syncthreads();
    for (int d = 128; d > 0; d >>= 1) {
        if (t < d) red[t] += red[t + d];
        __syncthreads();
    }
    if (t == 0) part[blockIdx.x] = red[0];
}

__global__ void k_scan_part(int* __restrict__ part, int nb) {
    int lane = threadIdx.x;
    int v = (lane < nb) ? part[lane] : 0;
    int incl = v;
    #pragma unroll
    for (int d = 1; d < 64; d <<= 1) {
        int u = __shfl_up(incl, d, 64);
        if (lane >= d) incl += u;
    }
    if (lane < nb) part[lane] = incl - v;
}

__global__ void k_scan_chunks(const int* __restrict__ cnt, const int* __restrict__ part,
                              int* __restrict__ off) {
    __shared__ int wtot[4];
    __shared__ int wexc[4];
    int t = threadIdx.x, b = blockIdx.x;
    int base = b * 2048 + t * 8;
    int4 a = {0, 0, 0, 0}, c = {0, 0, 0, 0};
    if (base < N_NODES) {
        const int4* p = (const int4*)(cnt + base);
        a = p[0];
        c = p[1];
    }
    int s0 = a.x, s1 = s0 + a.y, s2 = s1 + a.z, s3 = s2 + a.w;
    int s4 = s3 + c.x, s5 = s4 + c.y, s6 = s5 + c.z, s7 = s6 + c.w;
    int tot = s7;
    int lane = t & 63, wid = t >> 6;
    int incl = tot;
    #pragma unroll
    for (int d = 1; d < 64; d <<= 1) {
        int u = __shfl_up(incl, d, 64);
        if (lane >= d) incl += u;
    }
    if (lane == 63) wtot[wid] = incl;
    __syncthreads();
    if (t == 0) {
        int r = 0;
        for (int i = 0; i < 4; i++) { int v = wtot[i]; wexc[i] = r; r += v; }
    }
    __syncthreads();
    int texc = incl - tot + wexc[wid] + part[b];
    if (base < N_NODES) {
        int4 o0 = {texc, texc + s0, texc + s1, texc + s2};
        int4 o1 = {texc + s3, texc + s4, texc + s5, texc + s6};
        ((int4*)(off + base))[0] = o0;
        ((int4*)(off + base))[1] = o1;
    }
}

__global__ void k_scatter64(const int* __restrict__ dst, const int* __restrict__ src,
                            const int* __restrict__ off, int* __restrict__ cur,
                            unsigned long long* __restrict__ code64) {
    int e = blockIdx.x * blockDim.x + threadIdx.x;
    if (e < N_EDGES) {
        int d = dst[e];
        int p = off[d] + atomicAdd(&cur[d], 1);
        code64[p] = ((unsigned long long)(unsigned)src[e] << 32) | (unsigned)e;
    }
}

__global__ void k_scatter32(const int* __restrict__ dst, const int* __restrict__ off,
                            int* __restrict__ cur, int* __restrict__ eid) {
    int e = blockIdx.x * blockDim.x + threadIdx.x;
    if (e < N_EDGES) {
        int d = dst[e];
        int p = off[d] + atomicAdd(&cur[d], 1);
        eid[p] = e;
    }
}

// ---------------- weight fold -> bf16 fused weight Wf[o][0..191] ----------------
// Wf[o][k<64] = Wa[o][k]; Wf[o][64+m] = sum_j Wa[o][64+j]*Wm[j][m].
// bc[o] = ba[o] + sum_j Wa[o][64+j]*bm[j].
__device__ __forceinline__ unsigned short f2bf(float f) {
    unsigned u = __float_as_uint(f);
    return (unsigned short)((u + 0x7FFFu + ((u >> 16) & 1u)) >> 16);
}

__global__ void k_prec(const float* __restrict__ Wm, const float* __restrict__ bm,
                       const float* __restrict__ Wa, const float* __restrict__ ba,
                       unsigned short* __restrict__ Wf, float* __restrict__ bc) {
    int o = blockIdx.x;       // 64
    int k = threadIdx.x;      // 192
    const float* war = Wa + o * 128 + 64;
    float w;
    if (k < 64) {
        w = Wa[o * 128 + k];
    } else {
        int m = k - 64;
        float s = 0.f;
        #pragma unroll 8
        for (int j = 0; j < 64; j++) s += war[j] * Wm[j * 128 + m];
        w = s;
    }
    Wf[o * 192 + k] = f2bf(w);
    if (k == 0) {
        float t = ba[o];
        for (int j = 0; j < 64; j++) t += war[j] * bm[j];
        bc[o] = t;
    }
}

// ---------------- fused: wave-per-node agg -> LDS bf16 -> MFMA apply ----------------
__device__ __forceinline__ float4 ld_feat(const float* __restrict__ nf,
                                          const float* __restrict__ ef,
                                          unsigned long long c, int slot) {
    unsigned e = (unsigned)c;
    unsigned sv = (unsigned)(c >> 32);
    const float* p = (slot < 16) ? (nf + (size_t)sv * 64 + slot * 4)
                                 : (ef + (size_t)e * 64 + (slot - 16) * 4);
    return *(const float4*)p;
}

__device__ __forceinline__ void st_bf4(unsigned short* p, float4 v) {
    unsigned lo = (unsigned)f2bf(v.x) | ((unsigned)f2bf(v.y) << 16);
    unsigned hi = (unsigned)f2bf(v.z) | ((unsigned)f2bf(v.w) << 16);
    uint2 u = {lo, hi};
    *(uint2*)p = u;
}

// 1024 threads = 16 waves = 16 nodes/block. N_NODES = 6250 * 16 exactly.
// Phase 1 (per wave, = proven k_agg): register-acc gather over CSR edges,
//   shfl_xor(32) combine; half-0 lanes write mean (bf16) -> cat[w][64..192),
//   half-1 lanes (slot<16) convert h=nf[n] -> cat[w][0..64).
// Phase 2: waves 0-3 run the r6 MFMA (cb = wave), epilogue bias+relu.
__global__ __launch_bounds__(1024) void k_fused(
    const float* __restrict__ nf, const float* __restrict__ ef,
    const int* __restrict__ cnt, const int* __restrict__ off,
    const unsigned long long* __restrict__ code64,
    const unsigned short* __restrict__ Wf,
    const float* __restrict__ ba, const float* __restrict__ bc,
    float* __restrict__ out) {
    __shared__ __align__(16) unsigned short cat[16][200];
    __shared__ __align__(16) unsigned short wt[64][200];
    __shared__ float degl[16];

    int tid = threadIdx.x, lane = tid & 63, w = tid >> 6;
    int base = blockIdx.x * 16;
    int n = base + w;

    // stage weights (64x192 bf16 = 6144 dwords) coalesced across 1024 threads
    {
        const unsigned* Wfu = (const unsigned*)Wf;
        #pragma unroll
        for (int r = 0; r < 6; r++) {
            int u = r * 1024 + tid;    // 0..6143
            int o = u / 96;            // 96 dwords per row
            int c = u - o * 96;
            *(unsigned*)&wt[o][2 * c] = Wfu[u];
        }
    }

    // ---- phase 1: aggregation (register acc, deep load pipelining) ----
    int slot = lane & 31, half = lane >> 5;
    int st = off[n], deg = cnt[n];
    int pend = st + deg;
    float4 acc = make_float4(0.f, 0.f, 0.f, 0.f);
    int p = st + half;
    for (; p + 6 < pend; p += 8) {
        unsigned long long c0 = code64[p];
        unsigned long long c1 = code64[p + 2];
        unsigned long long c2 = code64[p + 4];
        unsigned long long c3 = code64[p + 6];
        float4 a0 = ld_feat(nf, ef, c0, slot);
        float4 a1 = ld_feat(nf, ef, c1, slot);
        float4 a2 = ld_feat(nf, ef, c2, slot);
        float4 a3 = ld_feat(nf, ef, c3, slot);
        acc.x += a0.x + a1.x + a2.x + a3.x;
        acc.y += a0.y + a1.y + a2.y + a3.y;
        acc.z += a0.z + a1.z + a2.z + a3.z;
        acc.w += a0.w + a1.w + a2.w + a3.w;
    }
    for (; p < pend; p += 2) {
        unsigned long long c = code64[p];
        float4 a = ld_feat(nf, ef, c, slot);
        acc.x += a.x; acc.y += a.y; acc.z += a.z; acc.w += a.w;
    }
    acc.x += __shfl_xor(acc.x, 32, 64);
    acc.y += __shfl_xor(acc.y, 32, 64);
    acc.z += __shfl_xor(acc.z, 32, 64);
    acc.w += __shfl_xor(acc.w, 32, 64);

    if (half == 0) {
        float inv = (deg > 0) ? 1.f / (float)deg : 0.f;
        acc.x *= inv; acc.y *= inv; acc.z *= inv; acc.w *= inv;
        st_bf4(&cat[w][64 + slot * 4], acc);           // mean -> cols 64..192
    } else if (slot < 16) {
        float4 hv = ((const float4*)(nf + (size_t)n * 64))[slot];
        st_bf4(&cat[w][slot * 4], hv);                 // h -> cols 0..64
    }
    if (lane == 0) degl[w] = (float)deg;
    __syncthreads();

    // ---- phase 2: MFMA apply (waves 0-3 only) ----
    if (w >= 4) return;
    int cb = w;
    int lr = lane & 15;   // A row (node) / B row (output within block cb)
    int lg = lane >> 4;   // k-group

    bf16x8 a[6];
    #pragma unroll
    for (int ks = 0; ks < 6; ks++)
        a[ks] = *(const bf16x8*)&cat[lr][ks * 32 + lg * 8];

    f32x4 accd = {0.f, 0.f, 0.f, 0.f};
    #pragma unroll
    for (int ks = 0; ks < 6; ks++) {
        bf16x8 b = *(const bf16x8*)&wt[cb * 16 + lr][ks * 32 + lg * 8];
        accd = __builtin_amdgcn_mfma_f32_16x16x32_bf16(a[ks], b, accd, 0, 0, 0);
    }
    int o = cb * 16 + lr;
    float bcv = bc[o], bav = ba[o];
    // C/D: col=lane&15 (=o), row=(lane>>4)*4+r (=node)
    #pragma unroll
    for (int r = 0; r < 4; r++) {
        int nn = base + lg * 4 + r;
        float dv = degl[lg * 4 + r];
        float v = accd[r] + ((dv > 0.f) ? bcv : bav);
        out[(size_t)nn * 64 + o] = fmaxf(v, 0.f);
    }
}

// ---------------- fallback (round-1 kernel, known good) ----------------
__global__ __launch_bounds__(256) void k_node_fb(
    const float* __restrict__ nf, const float* __restrict__ ef,
    const int* __restrict__ src, const int* __restrict__ cnt,
    const int* __restrict__ off, const int* __restrict__ eid,
    const float* __restrict__ Wm, const float* __restrict__ bm,
    const float* __restrict__ Wa, const float* __restrict__ ba,
    float* __restrict__ out) {
    __shared__ __align__(16) float agg[64][132];
    __shared__ __align__(16) float hn[64][68];
    __shared__ float degl[64];

    int tid = threadIdx.x, lane = tid & 63, wid = tid >> 6;
    int base = blockIdx.x * 64;

    for (int q = 0; q < 16; q++) {
        int nl = wid * 16 + q;
        int n = base + nl;
        float sh = 0.f, se = 0.f;
        int dg = 0;
        if (n < N_NODES) {
            dg = cnt[n];
            int st = off[n];
            for (int c0 = 0; c0 < dg; c0 += 64) {
                int m = dg - c0;
                if (m > 64) m = 64;
                int e_l = 0, s_l = 0;
                if (lane < m) {
                    e_l = eid[st + c0 + lane];
                    s_l = src[e_l];
                }
                for (int j = 0; j < m; j++) {
                    int e = __shfl(e_l, j, 64);
                    int s = __shfl(s_l, j, 64);
                    sh += nf[(size_t)s * 64 + lane];
                    se += ef[(size_t)e * 64 + lane];
                }
            }
        }
        agg[nl][lane] = sh;
        agg[nl][64 + lane] = se;
        if (lane == 0) degl[nl] = (float)dg;
    }
    __syncthreads();

    int og = (tid & 15) * 4;
    int ng = (tid >> 4) * 4;
    float acc[4][4] = {};
    const float4* Wm4 = (const float4*)Wm;
    #pragma unroll 4
    for (int k4 = 0; k4 < 32; k4++) {
        float4 av[4], wv[4];
        #pragma unroll
        for (int i = 0; i < 4; i++) av[i] = *(const float4*)&agg[ng + i][k4 * 4];
        #pragma unroll
        for (int j = 0; j < 4; j++) wv[j] = Wm4[(og + j) * 32 + k4];
        #pragma unroll
        for (int i = 0; i < 4; i++)
            #pragma unroll
            for (int j = 0; j < 4; j++)
                acc[i][j] += av[i].x * wv[j].x + av[i].y * wv[j].y +
                             av[i].z * wv[j].z + av[i].w * wv[j].w;
    }
    #pragma unroll
    for (int i = 0; i < 4; i++) {
        float d = degl[ng + i];
        float inv = (d > 0.f) ? 1.f / d : 0.f;
        #pragma unroll
        for (int j = 0; j < 4; j++) {
            float v = (d > 0.f) ? acc[i][j] * inv + bm[og + j] : 0.f;
            hn[ng + i][og + j] = v;
        }
    }
    __syncthreads();

    float acc2[4][4] = {};
    const float4* Wa4 = (const float4*)Wa;
    #pragma unroll 4
    for (int k4 = 0; k4 < 16; k4++) {
        float4 hv[4], wv[4];
        #pragma unroll
        for (int i = 0; i < 4; i++) {
            int n = base + ng + i;
            if (n < N_NODES)
                hv[i] = ((const float4*)(nf + (size_t)n * 64))[k4];
            else
                hv[i] = make_float4(0.f, 0.f, 0.f, 0.f);
        }
        #pragma unroll
        for (int j = 0; j < 4; j++) wv[j] = Wa4[(og + j) * 32 + k4];
        #pragma unroll
        for (int i = 0; i < 4; i++)
            #pragma unroll
            for (int j = 0; j < 4; j++)
                acc2[i][j] += hv[i].x * wv[j].x + hv[i].y * wv[j].y +
                              hv[i].z * wv[j].z + hv[i].w * wv[j].w;
    }
    #pragma unroll 4
    for (int k4 = 0; k4 < 16; k4++) {
        float4 hv[4], wv[4];
        #pragma unroll
        for (int i = 0; i < 4; i++) hv[i] = *(const float4*)&hn[ng + i][k4 * 4];
        #pragma unroll
        for (int j = 0; j < 4; j++) wv[j] = Wa4[(og + j) * 32 + 16 + k4];
        #pragma unroll
        for (int i = 0; i < 4; i++)
            #pragma unroll
            for (int j = 0; j < 4; j++)
                acc2[i][j] += hv[i].x * wv[j].x + hv[i].y * wv[j].y +
                              hv[i].z * wv[j].z + hv[i].w * wv[j].w;
    }
    #pragma unroll
    for (int i = 0; i < 4; i++) {
        int n = base + ng + i;
        if (n < N_NODES) {
            float4 o;
            o.x = fmaxf(acc2[i][0] + ba[og + 0], 0.f);
            o.y = fmaxf(acc2[i][1] + ba[og + 1], 0.f);
            o.z = fmaxf(acc2[i][2] + ba[og + 2], 0.f);
            o.w = fmaxf(acc2[i][3] + ba[og + 3], 0.f);
            *(float4*)&out[(size_t)n * 64 + og] = o;
        }
    }
}

extern "C" void kernel_launch(void* const* d_in, const int* in_sizes, int n_in,
                              void* d_out, int out_size, void* d_ws, size_t ws_size,
                              hipStream_t stream) {
    const float* nf = (const float*)d_in[0];
    const float* ef = (const float*)d_in[1];
    const int* src = (const int*)d_in[2];
    const int* dst = (const int*)d_in[3];
    const float* Wm = (const float*)d_in[4];
    const float* bm = (const float*)d_in[5];
    const float* Wa = (const float*)d_in[6];
    const float* ba = (const float*)d_in[7];
    float* out = (float*)d_out;

    // ws layout: cnt[N], cur[N], part[64] (zeroed), off[N], code64[E], Wf[64*192] bf16, bc[64]
    int* cnt = (int*)d_ws;
    int* cur = cnt + N_NODES;
    int* part = cur + N_NODES;
    int* off = part + 64;
    size_t csr_bytes = (size_t)(3 * N_NODES + 64) * 4;  // 8B-aligned

    int nz = 2 * N_NODES + 64;  // cnt, cur, part
    k_zero<<<(nz + 255) / 256, 256, 0, stream>>>(cnt, nz);
    k_count<<<(N_EDGES + 255) / 256, 256, 0, stream>>>(dst, cnt);
    k_partial<<<NB_SCAN, 256, 0, stream>>>(cnt, part);
    k_scan_part<<<1, 64, 0, stream>>>(part, NB_SCAN);
    k_scan_chunks<<<NB_SCAN, 256, 0, stream>>>(cnt, part, off);

    size_t need = csr_bytes + (size_t)N_EDGES * 8 + (size_t)64 * 192 * 2 + 512;
    if (ws_size >= need) {
        unsigned long long* code64 = (unsigned long long*)((char*)d_ws + csr_bytes);
        unsigned short* Wf = (unsigned short*)((char*)code64 + (size_t)N_EDGES * 8);
        float* bc = (float*)(Wf + 64 * 192);
        k_prec<<<64, 192, 0, stream>>>(Wm, bm, Wa, ba, Wf, bc);
        k_scatter64<<<(N_EDGES + 255) / 256, 256, 0, stream>>>(dst, src, off, cur, code64);
        k_fused<<<N_NODES / 16, 1024, 0, stream>>>(nf, ef, cnt, off, code64, Wf, ba, bc, out);
    } else {
        int* eid = (int*)((char*)d_ws + csr_bytes);
        k_scatter32<<<(N_EDGES + 255) / 256, 256, 0, stream>>>(dst, off, cur, eid);
        k_node_fb<<<(N_NODES + 63) / 64, 256, 0, stream>>>(nf, ef, src, cnt, off, eid,
                                                           Wm, bm, Wa, ba, out);
    }
}